// Round 8
// baseline (288.472 us; speedup 1.0000x reference)
//
#include <hip/hip_runtime.h>
#include <math.h>

#define BB 8
#define HH 56
#define WWD 56
#define NN 3136
#define CC 256
#define DIMM 512
#define NHEAD 8
#define NQ 64
#define EPSF 1e-5f
#define SCALEF 0.04419417382415922f

typedef __attribute__((ext_vector_type(8))) short short8;
typedef __attribute__((ext_vector_type(4))) short short4v;
typedef __attribute__((ext_vector_type(4))) float floatx4;

// Fast erf-based gelu: Abramowitz-Stegun 7.1.26, |eps| <= 1.5e-7 (abs).
__device__ __forceinline__ float gelu_f(float x) {
    float z = x * 0.70710678118654752f;
    float a = fabsf(z);
    float t = __builtin_amdgcn_rcpf(1.f + 0.3275911f * a);
    float p = t * (0.254829592f + t * (-0.284496736f + t * (1.421413741f +
              t * (-1.453152027f + t * 1.061405429f))));
    float e = exp2f(-1.44269504f * a * a);
    float erfa = 1.f - p * e;
    float erfz = copysignf(erfa, z);
    return 0.5f * x * (1.f + erfz);
}
__device__ __forceinline__ unsigned short f2bf(float f) {
    union { float f; unsigned u; } v; v.f = f;
    return (unsigned short)((v.u + 0x7fffu + ((v.u >> 16) & 1u)) >> 16);
}
__device__ __forceinline__ float bf2f(unsigned short u) {
    union { unsigned u; float f; } v; v.u = ((unsigned)u) << 16;
    return v.f;
}

// Stage a 128x64 fp32 weight tile into LDS as bf16, 72-short padded rows.
__device__ __forceinline__ void stage_w_f32(const float* __restrict__ wsrc,
                                            int rowlen, int c0, int k0,
                                            short* __restrict__ Bs, int tid) {
    int c = tid >> 1;
    int ob = (tid & 1) * 4;
    const float* src = wsrc + (size_t)(c0 + c) * rowlen + k0 + ob * 8;
    short* dst = &Bs[c * 72 + ob * 8];
#pragma unroll
    for (int i2 = 0; i2 < 4; i2++) {
        floatx4 f0 = *(const floatx4*)(src + i2 * 8);
        floatx4 f1 = *(const floatx4*)(src + i2 * 8 + 4);
        short8 pk;
        pk[0] = (short)f2bf(f0[0]); pk[1] = (short)f2bf(f0[1]);
        pk[2] = (short)f2bf(f0[2]); pk[3] = (short)f2bf(f0[3]);
        pk[4] = (short)f2bf(f1[0]); pk[5] = (short)f2bf(f1[1]);
        pk[6] = (short)f2bf(f1[2]); pk[7] = (short)f2bf(f1[3]);
        *(short8*)(dst + i2 * 8) = pk;
    }
}

// ===========================================================================
// L1: gemm_v (128x128 tile, m-major) with fp32 weight staging,
// co-launched with the w16c3/w16p casts (independent blocks).
// bid < 392: gemm (n_t = bid%196, c_t = bid/196); else cast.
// ===========================================================================
__global__ __launch_bounds__(256) void l1_gemmv_cast(
    const float* __restrict__ x, const float* __restrict__ wv_f32,
    unsigned short* __restrict__ v16,
    const float* __restrict__ proj_w, const float* __restrict__ conv3_w,
    unsigned short* __restrict__ w16p, unsigned short* __restrict__ w16c3) {
    __shared__ short Ws[128 * 72];
    __shared__ short Xs[128 * 72];
    int bid = blockIdx.x;
    int tid = threadIdx.x;
    if (bid >= 392) {
        int start = (bid - 392) * 1024;
        int end = start + 1024;
        if (end > 327680) end = 327680;
        for (int i = start + tid; i < end; i += 256) {
            if (i < 262144) w16p[i] = f2bf(proj_w[i]);
            else w16c3[i - 262144] = f2bf(conv3_w[i - 262144]);
        }
        return;
    }
    int n0 = (bid % 196) * 128, c0 = (bid / 196) * 128;
    int lane = tid & 63, wv = tid >> 6;
    int wc = wv >> 1, wn = wv & 1;
    int quad = lane >> 4, l16 = lane & 15;
    floatx4 zero = {0.f, 0.f, 0.f, 0.f};
    floatx4 acc[4][4];
#pragma unroll
    for (int ci = 0; ci < 4; ci++)
#pragma unroll
        for (int ni = 0; ni < 4; ni++) acc[ci][ni] = zero;

    for (int k0 = 0; k0 < 256; k0 += 64) {
        {
            int m = tid >> 1;
            int ob = (tid & 1) * 4;
            const float* src = x + (size_t)(n0 + m) * DIMM + k0 + ob * 8;
            short* dst = &Xs[m * 72 + ob * 8];
#pragma unroll
            for (int i2 = 0; i2 < 4; i2++) {
                floatx4 f0 = *(const floatx4*)(src + i2 * 8);
                floatx4 f1 = *(const floatx4*)(src + i2 * 8 + 4);
                short8 pk;
                pk[0] = (short)f2bf(f0[0]); pk[1] = (short)f2bf(f0[1]);
                pk[2] = (short)f2bf(f0[2]); pk[3] = (short)f2bf(f0[3]);
                pk[4] = (short)f2bf(f1[0]); pk[5] = (short)f2bf(f1[1]);
                pk[6] = (short)f2bf(f1[2]); pk[7] = (short)f2bf(f1[3]);
                *(short8*)(dst + i2 * 8) = pk;
            }
        }
        stage_w_f32(wv_f32, 256, c0, k0, Ws, tid);
        __syncthreads();
#pragma unroll
        for (int kc = 0; kc < 2; kc++) {
            short8 af[4], bf[4];
#pragma unroll
            for (int ci = 0; ci < 4; ci++)
                af[ci] = *(const short8*)&Ws[(wc * 64 + ci * 16 + l16) * 72 + (kc * 4 + quad) * 8];
#pragma unroll
            for (int ni = 0; ni < 4; ni++)
                bf[ni] = *(const short8*)&Xs[(wn * 64 + ni * 16 + l16) * 72 + (kc * 4 + quad) * 8];
#pragma unroll
            for (int ci = 0; ci < 4; ci++)
#pragma unroll
                for (int ni = 0; ni < 4; ni++)
                    acc[ci][ni] = __builtin_amdgcn_mfma_f32_16x16x32_bf16(
                        af[ci], bf[ni], acc[ci][ni], 0, 0, 0);
        }
        __syncthreads();
    }
#pragma unroll
    for (int ni = 0; ni < 4; ni++) {
        int ng = n0 + wn * 64 + ni * 16 + l16;
        int b = ng / NN, n = ng - b * NN;
#pragma unroll
        for (int ci = 0; ci < 4; ci++) {
#pragma unroll
            for (int r = 0; r < 4; r++) {
                int c = c0 + wc * 64 + ci * 16 + quad * 4 + r;
                v16[((size_t)b * CC + c) * NN + n] = f2bf(acc[ci][ni][r]);
            }
        }
    }
}

// 3x3 depthwise tap with local-row indexing and global y-guards.
__device__ __forceinline__ float dw3x3g(const float* __restrict__ Us, int lr,
                                        int x, bool ym, bool yp,
                                        float w0, float w1, float w2, float w3,
                                        float w4, float w5, float w6, float w7,
                                        float w8) {
    bool xm = x > 0, xp = x < 55;
    const float* r1 = &Us[(lr - 1) * 57 + x];
    const float* r2 = &Us[lr * 57 + x];
    const float* r3 = &Us[(lr + 1) * 57 + x];
    float acc = r2[0] * w4;
    if (xm) acc += r2[-1] * w3;
    if (xp) acc += r2[1] * w5;
    if (ym) {
        acc += r1[0] * w1;
        if (xm) acc += r1[-1] * w0;
        if (xp) acc += r1[1] * w2;
    }
    if (yp) {
        acc += r3[0] * w7;
        if (xm) acc += r3[-1] * w6;
        if (xp) acc += r3[1] * w8;
    }
    return acc;
}

// ===========================================================================
// dwconv2x: fused dwconv1+bn1 -> pools(q) -> gelu -> dwconv2+bn2 -> pools(k).
// 4 row-chunks per (b,c), 8192 blocks.
// ===========================================================================
__global__ __launch_bounds__(256) void dwconv2x_k(
    const unsigned short* __restrict__ in,
    const float* __restrict__ w1c, const float* __restrict__ g1,
    const float* __restrict__ b1, const float* __restrict__ m1,
    const float* __restrict__ v1,
    const float* __restrict__ w2c, const float* __restrict__ g2,
    const float* __restrict__ b2, const float* __restrict__ m2,
    const float* __restrict__ v2,
    unsigned short* __restrict__ out,
    float* __restrict__ oavg1, float* __restrict__ omax1,
    float* __restrict__ oavg2, float* __restrict__ omax2) {
    __shared__ float Us[18 * 57];
    __shared__ float Cs[16 * 57];
    int bid = blockIdx.x;
    int bc = bid >> 2, chunk = bid & 3;
    int c = bc & 255;
    int r0 = chunk * 14;
    int tid = threadIdx.x;
    const unsigned short* ip = in + (size_t)bc * NN;

    int gl0 = max(r0 - 2, 0), gh0 = min(r0 + 15, 55);
    int nin = (gh0 - gl0 + 1) * 56;
    const unsigned short* ipb = ip + gl0 * 56;
    {
        int e = tid * 4;
        if (e < nin) {
            short4v pk = *(const short4v*)(const short*)(ipb + e);
#pragma unroll
            for (int j = 0; j < 4; j++) {
                int el = e + j;
                int ry = el / 56, x = el - ry * 56;
                int lr = (gl0 + ry) - (r0 - 2);
                Us[lr * 57 + x] = bf2f((unsigned short)pk[j]);
            }
        }
    }
    float w0 = w1c[c * 9 + 0], w1 = w1c[c * 9 + 1], w2 = w1c[c * 9 + 2];
    float w3 = w1c[c * 9 + 3], w4 = w1c[c * 9 + 4], w5 = w1c[c * 9 + 5];
    float w6 = w1c[c * 9 + 6], w7 = w1c[c * 9 + 7], w8 = w1c[c * 9 + 8];
    float s = g1[c] * rsqrtf(v1[c] + EPSF);
    float sh = b1[c] - m1[c] * s;
    __syncthreads();
    int c1lo = max(r0 - 1, 0), c1hi = min(r0 + 14, 55);
    int n1 = (c1hi - c1lo + 1) * 56;
    for (int i = tid; i < n1; i += 256) {
        int ry = i / 56, x = i - ry * 56;
        int gr = c1lo + ry;
        int liu = gr - (r0 - 2);
        float acc = dw3x3g(Us, liu, x, gr > 0, gr < 55,
                           w0, w1, w2, w3, w4, w5, w6, w7, w8);
        Cs[(gr - (r0 - 1)) * 57 + x] = acc * s + sh;
    }
    __syncthreads();
    if (tid < 16) {
        int qy = 2 * chunk + (tid >> 3), qx = tid & 7;
        const float* p0 = &Cs[(qy * 7 - (r0 - 1)) * 57 + qx * 7];
        float sm = 0.f, mx = -INFINITY;
#pragma unroll
        for (int py = 0; py < 7; py++)
#pragma unroll
            for (int px = 0; px < 7; px++) {
                float t = p0[py * 57 + px];
                sm += t;
                mx = fmaxf(mx, t);
            }
        oavg1[(size_t)bc * 64 + qy * 8 + qx] = sm * (1.f / 49.f);
        omax1[(size_t)bc * 64 + qy * 8 + qx] = mx;
    }
    for (int i = tid; i < n1; i += 256) {
        int ry = i / 56, x = i - ry * 56;
        int lr1 = (c1lo + ry) - (r0 - 1);
        Us[lr1 * 57 + x] = gelu_f(Cs[lr1 * 57 + x]);
    }
    w0 = w2c[c * 9 + 0]; w1 = w2c[c * 9 + 1]; w2 = w2c[c * 9 + 2];
    w3 = w2c[c * 9 + 3]; w4 = w2c[c * 9 + 4]; w5 = w2c[c * 9 + 5];
    w6 = w2c[c * 9 + 6]; w7 = w2c[c * 9 + 7]; w8 = w2c[c * 9 + 8];
    s = g2[c] * rsqrtf(v2[c] + EPSF);
    sh = b2[c] - m2[c] * s;
    __syncthreads();
    unsigned short* op = out + (size_t)bc * NN;
    for (int i = tid; i < 14 * 56; i += 256) {
        int ry = i / 56, x = i - ry * 56;
        int gr = r0 + ry;
        int lg = ry + 1;
        float val = dw3x3g(Us, lg, x, gr > 0, gr < 55,
                           w0, w1, w2, w3, w4, w5, w6, w7, w8) * s + sh;
        Cs[ry * 57 + x] = val;
        op[gr * 56 + x] = f2bf(val);
    }
    __syncthreads();
    if (tid < 16) {
        int qy = 2 * chunk + (tid >> 3), qx = tid & 7;
        const float* p0 = &Cs[((qy * 7) - r0) * 57 + qx * 7];
        float sm = 0.f, mx = -INFINITY;
#pragma unroll
        for (int py = 0; py < 7; py++)
#pragma unroll
            for (int px = 0; px < 7; px++) {
                float t = p0[py * 57 + px];
                sm += t;
                mx = fmaxf(mx, t);
            }
        oavg2[(size_t)bc * 64 + qy * 8 + qx] = sm * (1.f / 49.f);
        omax2[(size_t)bc * 64 + qy * 8 + qx] = mx;
    }
}

// ===========================================================================
// conv3 body (128m x 128c tile), LDS carved from smem (As@0, Bs@18432).
// mct in [0, 392): m_t = mct % 196, c_t = mct / 196.
// ===========================================================================
__device__ void conv3_body(
    char* smem, int mct,
    const unsigned short* __restrict__ xin, const unsigned short* __restrict__ w16,
    const float* __restrict__ bias, const float* __restrict__ g,
    const float* __restrict__ bparm, const float* __restrict__ mm,
    const float* __restrict__ vvv, unsigned short* __restrict__ out16) {
    short* As = (short*)smem;
    short* Bs = (short*)(smem + 18432);
    int m0 = (mct % 196) * 128, c0 = (mct / 196) * 128;
    int tid = threadIdx.x;
    int lane = tid & 63, wv = tid >> 6;
    int wm = wv >> 1, wc = wv & 1;
    int quad = lane >> 4, l16 = lane & 15;
    floatx4 zero = {0.f, 0.f, 0.f, 0.f};
    floatx4 acc[4][4];
#pragma unroll
    for (int mi = 0; mi < 4; mi++)
#pragma unroll
        for (int ci = 0; ci < 4; ci++) acc[mi][ci] = zero;

    for (int k0 = 0; k0 < 256; k0 += 64) {
#pragma unroll
        for (int i2 = 0; i2 < 4; i2++) {
            int mo = i2 * 4 + wv;
            int kk = lane;
            int m8 = m0 + mo * 8;
            int b8 = m8 / NN, n8 = m8 - b8 * NN;
            short8 pk = *(const short8*)(const short*)(
                xin + ((size_t)b8 * CC + (k0 + kk)) * NN + n8);
            short* dst = &As[(mo * 8) * 72 + kk];
#pragma unroll
            for (int j = 0; j < 8; j++) dst[j * 72] = pk[j];
        }
#pragma unroll
        for (int i2 = 0; i2 < 4; i2++) {
            int idx = tid + 256 * i2;
            int c = idx >> 3, o = idx & 7;
            *(short8*)&Bs[c * 72 + o * 8] =
                *(const short8*)(const short*)(w16 + (size_t)(c0 + c) * CC + k0 + o * 8);
        }
        __syncthreads();
#pragma unroll
        for (int kc = 0; kc < 2; kc++) {
            short8 af[4], bf[4];
#pragma unroll
            for (int mi = 0; mi < 4; mi++)
                af[mi] = *(const short8*)&As[(wm * 64 + mi * 16 + l16) * 72 + (kc * 4 + quad) * 8];
#pragma unroll
            for (int ci = 0; ci < 4; ci++)
                bf[ci] = *(const short8*)&Bs[(wc * 64 + ci * 16 + l16) * 72 + (kc * 4 + quad) * 8];
#pragma unroll
            for (int mi = 0; mi < 4; mi++)
#pragma unroll
                for (int ci = 0; ci < 4; ci++)
                    acc[mi][ci] = __builtin_amdgcn_mfma_f32_16x16x32_bf16(
                        af[mi], bf[ci], acc[mi][ci], 0, 0, 0);
        }
        __syncthreads();
    }
#pragma unroll
    for (int ci = 0; ci < 4; ci++) {
        int co = c0 + wc * 64 + ci * 16 + l16;
        float s = g[co] * rsqrtf(vvv[co] + EPSF);
        float sh = bparm[co] - mm[co] * s;
        float bi = bias[co];
#pragma unroll
        for (int mi = 0; mi < 4; mi++) {
            int mbase = m0 + wm * 64 + mi * 16 + quad * 4;
#pragma unroll
            for (int r = 0; r < 4; r++) {
                float val = gelu_f((acc[mi][ci][r] + bi) * s + sh);
                out16[(size_t)(mbase + r) * CC + co] = f2bf(val);
            }
        }
    }
}

// ===========================================================================
// L3: attn_qk (bid < 64) co-launched with conv3 blocks 0..127.
// ===========================================================================
__global__ __launch_bounds__(256) void l3_qk_conv3(
    const float* __restrict__ q1, const float* __restrict__ q2,
    const float* __restrict__ k1, const float* __restrict__ k2,
    float* __restrict__ attn_s, float* __restrict__ mq,
    const unsigned short* __restrict__ xin, const unsigned short* __restrict__ w16,
    const float* __restrict__ bias, const float* __restrict__ g,
    const float* __restrict__ bparm, const float* __restrict__ mm,
    const float* __restrict__ vvv, unsigned short* __restrict__ out16) {
    __shared__ __align__(16) char smem[36864];
    int bid = blockIdx.x;
    int tid = threadIdx.x;
    if (bid >= 64) {
        conv3_body(smem, bid - 64, xin, w16, bias, g, bparm, mm, vvv, out16);
        return;
    }
    float (*Qs)[64] = (float(*)[64])smem;
    float (*Ks)[64] = (float(*)[64])(smem + 16384);
    float (*pm)[64] = (float(*)[64])(smem + 32768);
    int b = bid >> 3, h = bid & 7;
#pragma unroll
    for (int l = 0; l < 16; l++) {
        int e = tid + 256 * l;
        int dt = e >> 6, i = e & 63;
        int d = dt & 31;
        const float* sq = (dt < 32) ? q1 : q2;
        const float* sk = (dt < 32) ? k1 : k2;
        Qs[dt][i] = sq[((size_t)b * CC + h * 32 + d) * NQ + i];
        Ks[dt][i] = sk[((size_t)b * CC + h * 32 + d) * NQ + i];
    }
    __syncthreads();
    int i = tid & 63, jg = tid >> 6;
    float acc[16] = {};
    for (int dt = 0; dt < 64; dt++) {
        float qv = Qs[dt][i];
#pragma unroll
        for (int t = 0; t < 16; t++) acc[t] += qv * Ks[dt][jg * 16 + t];
    }
    float mx = -INFINITY;
#pragma unroll
    for (int t = 0; t < 16; t++) {
        acc[t] *= SCALEF;
        mx = fmaxf(mx, acc[t]);
    }
    pm[jg][i] = mx;
    float* outp = attn_s + (((size_t)(b * 8 + h) * 64 + i) * 64) + jg * 16;
#pragma unroll
    for (int t = 0; t < 16; t++) outp[t] = acc[t];
    __syncthreads();
    if (tid < 64) {
        float m = fmaxf(fmaxf(pm[0][tid], pm[1][tid]),
                        fmaxf(pm[2][tid], pm[3][tid]));
        mq[(size_t)(b * 8 + h) * 64 + tid] = m;
    }
}

// ===========================================================================
// L4: attn_pv (bid < 448: s = bid%7, bh = bid/7) co-launched with conv3
// blocks 128..391.
// ===========================================================================
__global__ __launch_bounds__(256) void l4_pv_conv3(
    const float* __restrict__ attn_s, const float* __restrict__ mq,
    const unsigned short* __restrict__ v16,
    float* __restrict__ part_O, float* __restrict__ part_rs,
    const unsigned short* __restrict__ xin, const unsigned short* __restrict__ w16,
    const float* __restrict__ bias, const float* __restrict__ g,
    const float* __restrict__ bparm, const float* __restrict__ mm,
    const float* __restrict__ vvv, unsigned short* __restrict__ out16) {
    __shared__ __align__(16) char smem[57344];
    int bid = blockIdx.x;
    int tid = threadIdx.x;
    if (bid >= 448) {
        conv3_body(smem, 128 + bid - 448, xin, w16, bias, g, bparm, mm, vvv, out16);
        return;
    }
    float (*asub)[68] = (float(*)[68])smem;                        // 17408 B
    unsigned short (*Vs)[456] = (unsigned short(*)[456])(smem + 17408);  // 29184 B
    short (*po4)[4] = (short(*)[4])(smem + 46592);                 // 3584 B
    float (*pw4)[4] = (float(*)[4])(smem + 50176);                 // 7168 B
    int s = bid % 7, bh = bid / 7;
    int b = bh >> 3, h = bh & 7;
    int lane = tid & 63, wv = tid >> 6;
    int quad = lane >> 4, l16 = lane & 15;
    int q = wv * 16 + l16;
    float Mv = mq[(size_t)bh * 64 + q];
    {
        int qq = tid & 63, jg = tid >> 6;
        const float* src = attn_s + ((size_t)bh * 64 + qq) * 64 + jg * 16;
        float* dst = &asub[qq][jg * 16];
#pragma unroll
        for (int t = 0; t < 4; t++)
            *(floatx4*)(dst + t * 4) = *(const floatx4*)(src + t * 4);
    }
    {
        int d = tid >> 3, o0 = tid & 7;
        const unsigned short* vp =
            v16 + ((size_t)(b * CC + h * 32 + d)) * NN + s * 448;
#pragma unroll
        for (int t = 0; t < 7; t++) {
            int oc = o0 + t * 8;
            *(short8*)&Vs[d][oc * 8] = *(const short8*)(const short*)(vp + oc * 8);
        }
    }
    for (int idx = tid; idx < 448; idx += 256) {
        int n = s * 448 + idx;
        int oy = n / WWD, ox = n - oy * WWD;
        float sy = (oy + 0.5f) * 0.14285714285714285f - 0.5f;
        float sx = (ox + 0.5f) * 0.14285714285714285f - 0.5f;
        float fy0 = floorf(sy), fx0 = floorf(sx);
        int y0 = (int)fy0, x0 = (int)fx0;
        float fy = sy - fy0, fx = sx - fx0;
        int y0c = max(y0, 0), y1c = min(y0 + 1, 7);
        int x0c = max(x0, 0), x1c = min(x0 + 1, 7);
        po4[idx][0] = (short)(y0c * 8 + x0c);
        po4[idx][1] = (short)(y0c * 8 + x1c);
        po4[idx][2] = (short)(y1c * 8 + x0c);
        po4[idx][3] = (short)(y1c * 8 + x1c);
        pw4[idx][0] = (1.f - fy) * (1.f - fx);
        pw4[idx][1] = (1.f - fy) * fx;
        pw4[idx][2] = fy * (1.f - fx);
        pw4[idx][3] = fy * fx;
    }
    __syncthreads();
    floatx4 zero = {0.f, 0.f, 0.f, 0.f};
    floatx4 acc0 = zero, acc1 = zero;
    float rsum = 0.f;
    for (int cch = 0; cch < 7; cch++) {
#pragma unroll
        for (int kc = 0; kc < 2; kc++) {
            int col = cch * 64 + kc * 32 + quad * 8;
            short8 af;
#pragma unroll
            for (int j = 0; j < 8; j++) {
                int np = col + j;
                float val = pw4[np][0] * asub[q][po4[np][0]]
                          + pw4[np][1] * asub[q][po4[np][1]]
                          + pw4[np][2] * asub[q][po4[np][2]]
                          + pw4[np][3] * asub[q][po4[np][3]];
                float p = exp2f((val - Mv) * 1.44269504f);
                rsum += p;
                af[j] = (short)f2bf(p);
            }
            short8 bf0 = *(const short8*)&Vs[l16][col];
            short8 bf1 = *(const short8*)&Vs[16 + l16][col];
            acc0 = __builtin_amdgcn_mfma_f32_16x16x32_bf16(af, bf0, acc0, 0, 0, 0);
            acc1 = __builtin_amdgcn_mfma_f32_16x16x32_bf16(af, bf1, acc1, 0, 0, 0);
        }
    }
    rsum += __shfl_xor(rsum, 16, 64);
    rsum += __shfl_xor(rsum, 32, 64);
    size_t base = ((size_t)bh * 7 + s) * 64;
    if (lane < 16) part_rs[base + wv * 16 + lane] = rsum;
#pragma unroll
    for (int nt = 0; nt < 2; nt++) {
        floatx4 a = nt ? acc1 : acc0;
#pragma unroll
        for (int r = 0; r < 4; r++) {
            int qo = wv * 16 + quad * 4 + r;
            part_O[(base + qo) * 32 + nt * 16 + l16] = a[r];
        }
    }
}

// ===========================================================================
// upconv: fused split-K reduction + bilinear upsample + dw 3x3 + vbn.
// ===========================================================================
__global__ __launch_bounds__(256) void upconv_k(
    const float* __restrict__ part_O, const float* __restrict__ part_rs,
    const float* __restrict__ w,
    const float* __restrict__ g, const float* __restrict__ bparm,
    const float* __restrict__ m, const float* __restrict__ v,
    unsigned short* __restrict__ xlow16) {
    __shared__ float ts[64];
    __shared__ float Us[16 * 57];
    int bid = blockIdx.x;
    int bc = bid >> 2, chunk = bid & 3;
    int c = bc & 255;
    int r0 = chunk * 14;
    int tid = threadIdx.x;
    if (tid < 64) {
        int h = c >> 5, d = c & 31;
        int bh = (bc >> 8) * 8 + h;
        float o = 0.f, rs = 0.f;
        for (int s7 = 0; s7 < 7; s7++) {
            size_t base = ((size_t)bh * 7 + s7) * 64 + tid;
            o += part_O[base * 32 + d];
            rs += part_rs[base];
        }
        ts[tid] = o / rs;
    }
    __syncthreads();
    int blo = max(r0 - 1, 0), bhi = min(r0 + 14, 55);
    int nb = (bhi - blo + 1) * 56;
    for (int i = tid; i < nb; i += 256) {
        int ry = i / 56, x = i - ry * 56;
        int gr = blo + ry;
        float sy = (gr + 0.5f) * 0.14285714285714285f - 0.5f;
        float sx = (x + 0.5f) * 0.14285714285714285f - 0.5f;
        float fy0 = floorf(sy), fx0 = floorf(sx);
        int y0 = (int)fy0, x0 = (int)fx0;
        float fy = sy - fy0, fx = sx - fx0;
        int y0c = max(y0, 0), y1c = min(y0 + 1, 7);
        int x0c = max(x0, 0), x1c = min(x0 + 1, 7);
        float v00 = ts[y0c * 8 + x0c], v01 = ts[y0c * 8 + x1c];
        float v10 = ts[y1c * 8 + x0c], v11 = ts[y1c * 8 + x1c];
        Us[(gr - (r0 - 1)) * 57 + x] =
            (1.f - fy) * ((1.f - fx) * v00 + fx * v01) +
            fy * ((1.f - fx) * v10 + fx * v11);
    }
    float w0 = w[c * 9 + 0], w1 = w[c * 9 + 1], w2 = w[c * 9 + 2];
    float w3 = w[c * 9 + 3], w4 = w[c * 9 + 4], w5 = w[c * 9 + 5];
    float w6 = w[c * 9 + 6], w7 = w[c * 9 + 7], w8 = w[c * 9 + 8];
    float s = g[c] * rsqrtf(v[c] + EPSF);
    float sh = bparm[c] - m[c] * s;
    __syncthreads();
    unsigned short* op = xlow16 + (size_t)bc * NN;
    for (int i = tid; i < 14 * 56; i += 256) {
        int ry = i / 56, x = i - ry * 56;
        int gr = r0 + ry;
        float val = dw3x3g(Us, ry + 1, x, gr > 0, gr < 55,
                           w0, w1, w2, w3, w4, w5, w6, w7, w8);
        op[gr * 56 + x] = f2bf(val * s + sh);
    }
}

// ===========================================================================
// proj: final projection MFMA (128x128 tile). Grid dim3(196, 4).
// ===========================================================================
__global__ __launch_bounds__(256) void proj_mfma(
    const unsigned short* __restrict__ xh16, const unsigned short* __restrict__ xl16,
    const unsigned short* __restrict__ w16, const float* __restrict__ bias,
    float* __restrict__ y) {
    __shared__ short As[128 * 72];
    __shared__ short Bs[128 * 72];
    int m0 = blockIdx.x * 128, c0 = blockIdx.y * 128;
    int tid = threadIdx.x;
    int lane = tid & 63, wv = tid >> 6;
    int wm = wv >> 1, wc = wv & 1;
    int quad = lane >> 4, l16 = lane & 15;
    floatx4 zero = {0.f, 0.f, 0.f, 0.f};
    floatx4 acc[4][4];
#pragma unroll
    for (int mi = 0; mi < 4; mi++)
#pragma unroll
        for (int ci = 0; ci < 4; ci++) acc[mi][ci] = zero;

    for (int k0 = 0; k0 < 512; k0 += 64) {
        if (k0 < 256) {
#pragma unroll
            for (int i2 = 0; i2 < 4; i2++) {
                int idx = tid + 256 * i2;
                int m = idx >> 3, o = idx & 7;
                *(short8*)&As[m * 72 + o * 8] =
                    *(const short8*)(const short*)(xh16 + (size_t)(m0 + m) * CC + k0 + o * 8);
            }
        } else {
#pragma unroll
            for (int i2 = 0; i2 < 4; i2++) {
                int mo = i2 * 4 + wv;
                int kk = lane;
                int m8 = m0 + mo * 8;
                int b8 = m8 / NN, n8 = m8 - b8 * NN;
                short8 pk = *(const short8*)(const short*)(
                    xl16 + ((size_t)b8 * CC + (k0 - 256 + kk)) * NN + n8);
                short* dst = &As[(mo * 8) * 72 + kk];
#pragma unroll
                for (int j = 0; j < 8; j++) dst[j * 72] = pk[j];
            }
        }
#pragma unroll
        for (int i2 = 0; i2 < 4; i2++) {
            int idx = tid + 256 * i2;
            int c = idx >> 3, o = idx & 7;
            *(short8*)&Bs[c * 72 + o * 8] =
                *(const short8*)(const short*)(w16 + (size_t)(c0 + c) * DIMM + k0 + o * 8);
        }
        __syncthreads();
#pragma unroll
        for (int kc = 0; kc < 2; kc++) {
            short8 af[4], bf[4];
#pragma unroll
            for (int mi = 0; mi < 4; mi++)
                af[mi] = *(const short8*)&As[(wm * 64 + mi * 16 + l16) * 72 + (kc * 4 + quad) * 8];
#pragma unroll
            for (int ci = 0; ci < 4; ci++)
                bf[ci] = *(const short8*)&Bs[(wc * 64 + ci * 16 + l16) * 72 + (kc * 4 + quad) * 8];
#pragma unroll
            for (int mi = 0; mi < 4; mi++)
#pragma unroll
                for (int ci = 0; ci < 4; ci++)
                    acc[mi][ci] = __builtin_amdgcn_mfma_f32_16x16x32_bf16(
                        af[mi], bf[ci], acc[mi][ci], 0, 0, 0);
        }
        __syncthreads();
    }
#pragma unroll
    for (int mi = 0; mi < 4; mi++) {
        int mbase = m0 + wm * 64 + mi * 16 + quad * 4;
#pragma unroll
        for (int ci = 0; ci < 4; ci++) {
            int co = c0 + wc * 64 + ci * 16 + l16;
            float bi = bias[co];
#pragma unroll
            for (int r = 0; r < 4; r++)
                y[(size_t)(mbase + r) * DIMM + co] = acc[mi][ci][r] + bi;
        }
    }
}

extern "C" void kernel_launch(void* const* d_in, const int* in_sizes, int n_in,
                              void* d_out, int out_size, void* d_ws, size_t ws_size,
                              hipStream_t stream) {
    const float* x        = (const float*)d_in[0];
    const float* proj_v_w = (const float*)d_in[1];
    const float* conv1_w  = (const float*)d_in[2];
    const float* conv2_w  = (const float*)d_in[3];
    const float* conv3_w  = (const float*)d_in[4];
    const float* conv3_b  = (const float*)d_in[5];
    const float* v_conv_w = (const float*)d_in[6];
    const float* proj_w   = (const float*)d_in[7];
    const float* proj_b   = (const float*)d_in[8];
    const float* bn1_g = (const float*)d_in[9],  *bn1_b = (const float*)d_in[10];
    const float* bn1_m = (const float*)d_in[11], *bn1_v = (const float*)d_in[12];
    const float* bn2_g = (const float*)d_in[13], *bn2_b = (const float*)d_in[14];
    const float* bn2_m = (const float*)d_in[15], *bn2_v = (const float*)d_in[16];
    const float* bn3_g = (const float*)d_in[17], *bn3_b = (const float*)d_in[18];
    const float* bn3_m = (const float*)d_in[19], *bn3_v = (const float*)d_in[20];
    const float* vbn_g = (const float*)d_in[21], *vbn_b = (const float*)d_in[22];
    const float* vbn_m = (const float*)d_in[23], *vbn_v = (const float*)d_in[24];

    const size_t big = (size_t)BB * CC * NN;  // 6,422,528 elements
    unsigned short* v16    = (unsigned short*)d_ws;       // v bf16 NCHW
    unsigned short* bufA16 = v16 + big;                   // (unused, layout kept)
    unsigned short* bufB16 = bufA16 + big;                // bn2 bf16 NCHW
    unsigned short* xh16   = bufB16 + big;                // x_high bf16 (B,N,C)
    unsigned short* xlow16 = xh16 + big;                  // x_low bf16 NCHW
    float* small = (float*)(xlow16 + big);
    float* q1 = small;
    float* q2 = q1 + (size_t)BB * CC * NQ;
    float* k1 = q2 + (size_t)BB * CC * NQ;
    float* k2 = k1 + (size_t)BB * CC * NQ;
    float* attn_s = k2 + (size_t)BB * CC * NQ;               // (B,NH,64,64)
    float* out_s  = attn_s + (size_t)BB * NHEAD * NQ * NQ;   // (unused)
    float* part_O = out_s + (size_t)BB * CC * NQ;            // 64*7*64*32
    float* part_rs = part_O + (size_t)64 * 7 * 64 * 32;      // 64*7*64
    float* mq = part_rs + (size_t)64 * 7 * 64;               // 64*64
    unsigned short* w16c3 = (unsigned short*)(mq + 64 * 64);
    unsigned short* w16p  = w16c3 + 65536;  // 262144 shorts

    // L1: gemm_v (fp32 weight staging) || cast w16p/w16c3
    l1_gemmv_cast<<<712, 256, 0, stream>>>(x, proj_v_w, v16,
                                           proj_w, conv3_w, w16p, w16c3);
    // L2
    dwconv2x_k<<<BB * CC * 4, 256, 0, stream>>>(
        v16, conv1_w, bn1_g, bn1_b, bn1_m, bn1_v,
        conv2_w, bn2_g, bn2_b, bn2_m, bn2_v, bufB16, q1, q2, k1, k2);
    // L3: qk || conv3[0:128)
    l3_qk_conv3<<<64 + 128, 256, 0, stream>>>(
        q1, q2, k1, k2, attn_s, mq,
        bufB16, w16c3, conv3_b, bn3_g, bn3_b, bn3_m, bn3_v, xh16);
    // L4: pv || conv3[128:392)
    l4_pv_conv3<<<448 + 264, 256, 0, stream>>>(
        attn_s, mq, v16, part_O, part_rs,
        bufB16, w16c3, conv3_b, bn3_g, bn3_b, bn3_m, bn3_v, xh16);
    // L5
    upconv_k<<<BB * CC * 4, 256, 0, stream>>>(part_O, part_rs, v_conv_w,
                                              vbn_g, vbn_b, vbn_m, vbn_v, xlow16);
    // L6
    proj_mfma<<<dim3(196, 4), 256, 0, stream>>>(xh16, xlow16, w16p, proj_b,
                                                (float*)d_out);
}

// Round 9
// 265.304 us; speedup vs baseline: 1.0873x; 1.0873x over previous
//
#include <hip/hip_runtime.h>
#include <math.h>

#define BB 8
#define HH 56
#define WWD 56
#define NN 3136
#define CC 256
#define DIMM 512
#define NHEAD 8
#define NQ 64
#define EPSF 1e-5f
#define SCALEF 0.04419417382415922f

typedef __attribute__((ext_vector_type(8))) short short8;
typedef __attribute__((ext_vector_type(4))) short short4v;
typedef __attribute__((ext_vector_type(4))) float floatx4;

// Fast erf-based gelu: Abramowitz-Stegun 7.1.26, |eps| <= 1.5e-7 (abs).
__device__ __forceinline__ float gelu_f(float x) {
    float z = x * 0.70710678118654752f;
    float a = fabsf(z);
    float t = __builtin_amdgcn_rcpf(1.f + 0.3275911f * a);
    float p = t * (0.254829592f + t * (-0.284496736f + t * (1.421413741f +
              t * (-1.453152027f + t * 1.061405429f))));
    float e = exp2f(-1.44269504f * a * a);
    float erfa = 1.f - p * e;
    float erfz = copysignf(erfa, z);
    return 0.5f * x * (1.f + erfz);
}
__device__ __forceinline__ unsigned short f2bf(float f) {
    union { float f; unsigned u; } v; v.f = f;
    return (unsigned short)((v.u + 0x7fffu + ((v.u >> 16) & 1u)) >> 16);
}
__device__ __forceinline__ float bf2f(unsigned short u) {
    union { unsigned u; float f; } v; v.u = ((unsigned)u) << 16;
    return v.f;
}

// Single kernel for all three weight casts.
__global__ __launch_bounds__(256) void cast3_k(
    const float* __restrict__ a, const float* __restrict__ b,
    const float* __restrict__ cc, unsigned short* __restrict__ da,
    unsigned short* __restrict__ db, unsigned short* __restrict__ dc) {
    int i = blockIdx.x * 256 + threadIdx.x;
    if (i < 65536) {
        da[i] = f2bf(a[i]);
        db[i] = f2bf(b[i]);
    }
    if (i < 262144) dc[i] = f2bf(cc[i]);
}

// ===========================================================================
// MFMA GEMM: v16[b,c,n] = bf16( sum_k x[(b*NN+n)*512+k] * w16[c*256+k] )
// Grid dim3(196, 2): x = n-tile (fastest), y = c-tile.
// ===========================================================================
__global__ __launch_bounds__(256) void gemm_v_mfma(
    const float* __restrict__ x, const unsigned short* __restrict__ w16,
    unsigned short* __restrict__ v16) {
    __shared__ short Ws[128 * 72];
    __shared__ short Xs[128 * 72];
    int n0 = blockIdx.x * 128, c0 = blockIdx.y * 128;
    int tid = threadIdx.x;
    int lane = tid & 63, wv = tid >> 6;
    int wc = wv >> 1, wn = wv & 1;
    int quad = lane >> 4, l16 = lane & 15;
    floatx4 zero = {0.f, 0.f, 0.f, 0.f};
    floatx4 acc[4][4];
#pragma unroll
    for (int ci = 0; ci < 4; ci++)
#pragma unroll
        for (int ni = 0; ni < 4; ni++) acc[ci][ni] = zero;

    for (int k0 = 0; k0 < 256; k0 += 64) {
        {
            int m = tid >> 1;
            int ob = (tid & 1) * 4;
            const float* src = x + (size_t)(n0 + m) * DIMM + k0 + ob * 8;
            short* dst = &Xs[m * 72 + ob * 8];
#pragma unroll
            for (int i2 = 0; i2 < 4; i2++) {
                floatx4 f0 = *(const floatx4*)(src + i2 * 8);
                floatx4 f1 = *(const floatx4*)(src + i2 * 8 + 4);
                short8 pk;
                pk[0] = (short)f2bf(f0[0]); pk[1] = (short)f2bf(f0[1]);
                pk[2] = (short)f2bf(f0[2]); pk[3] = (short)f2bf(f0[3]);
                pk[4] = (short)f2bf(f1[0]); pk[5] = (short)f2bf(f1[1]);
                pk[6] = (short)f2bf(f1[2]); pk[7] = (short)f2bf(f1[3]);
                *(short8*)(dst + i2 * 8) = pk;
            }
        }
#pragma unroll
        for (int i2 = 0; i2 < 4; i2++) {
            int idx = tid + 256 * i2;
            int c = idx >> 3, o = idx & 7;
            *(short8*)&Ws[c * 72 + o * 8] =
                *(const short8*)(const short*)(w16 + (size_t)(c0 + c) * 256 + k0 + o * 8);
        }
        __syncthreads();
#pragma unroll
        for (int kc = 0; kc < 2; kc++) {
            short8 af[4], bf[4];
#pragma unroll
            for (int ci = 0; ci < 4; ci++)
                af[ci] = *(const short8*)&Ws[(wc * 64 + ci * 16 + l16) * 72 + (kc * 4 + quad) * 8];
#pragma unroll
            for (int ni = 0; ni < 4; ni++)
                bf[ni] = *(const short8*)&Xs[(wn * 64 + ni * 16 + l16) * 72 + (kc * 4 + quad) * 8];
#pragma unroll
            for (int ci = 0; ci < 4; ci++)
#pragma unroll
                for (int ni = 0; ni < 4; ni++)
                    acc[ci][ni] = __builtin_amdgcn_mfma_f32_16x16x32_bf16(
                        af[ci], bf[ni], acc[ci][ni], 0, 0, 0);
        }
        __syncthreads();
    }
#pragma unroll
    for (int ni = 0; ni < 4; ni++) {
        int ng = n0 + wn * 64 + ni * 16 + l16;
        int b = ng / NN, n = ng - b * NN;
#pragma unroll
        for (int ci = 0; ci < 4; ci++) {
#pragma unroll
            for (int r = 0; r < 4; r++) {
                int c = c0 + wc * 64 + ci * 16 + quad * 4 + r;
                v16[((size_t)b * CC + c) * NN + n] = f2bf(acc[ci][ni][r]);
            }
        }
    }
}

// 3x3 depthwise tap with local-row indexing and global y-guards.
__device__ __forceinline__ float dw3x3g(const float* __restrict__ Us, int lr,
                                        int x, bool ym, bool yp,
                                        float w0, float w1, float w2, float w3,
                                        float w4, float w5, float w6, float w7,
                                        float w8) {
    bool xm = x > 0, xp = x < 55;
    const float* r1 = &Us[(lr - 1) * 57 + x];
    const float* r2 = &Us[lr * 57 + x];
    const float* r3 = &Us[(lr + 1) * 57 + x];
    float acc = r2[0] * w4;
    if (xm) acc += r2[-1] * w3;
    if (xp) acc += r2[1] * w5;
    if (ym) {
        acc += r1[0] * w1;
        if (xm) acc += r1[-1] * w0;
        if (xp) acc += r1[1] * w2;
    }
    if (yp) {
        acc += r3[0] * w7;
        if (xm) acc += r3[-1] * w6;
        if (xp) acc += r3[1] * w8;
    }
    return acc;
}

// ===========================================================================
// Fused dwconv1+bn1 -> pools(q) -> gelu -> dwconv2+bn2 -> pools(k) -> out.
// 4 row-chunks per (b,c), 8192 blocks.
// ===========================================================================
__global__ __launch_bounds__(256) void dwconv2x_k(
    const unsigned short* __restrict__ in,
    const float* __restrict__ w1c, const float* __restrict__ g1,
    const float* __restrict__ b1, const float* __restrict__ m1,
    const float* __restrict__ v1,
    const float* __restrict__ w2c, const float* __restrict__ g2,
    const float* __restrict__ b2, const float* __restrict__ m2,
    const float* __restrict__ v2,
    unsigned short* __restrict__ out,
    float* __restrict__ oavg1, float* __restrict__ omax1,
    float* __restrict__ oavg2, float* __restrict__ omax2) {
    __shared__ float Us[18 * 57];
    __shared__ float Cs[16 * 57];
    int bid = blockIdx.x;
    int bc = bid >> 2, chunk = bid & 3;
    int c = bc & 255;
    int r0 = chunk * 14;
    int tid = threadIdx.x;
    const unsigned short* ip = in + (size_t)bc * NN;

    int gl0 = max(r0 - 2, 0), gh0 = min(r0 + 15, 55);
    int nin = (gh0 - gl0 + 1) * 56;
    const unsigned short* ipb = ip + gl0 * 56;
    {
        int e = tid * 4;
        if (e < nin) {
            short4v pk = *(const short4v*)(const short*)(ipb + e);
#pragma unroll
            for (int j = 0; j < 4; j++) {
                int el = e + j;
                int ry = el / 56, x = el - ry * 56;
                int lr = (gl0 + ry) - (r0 - 2);
                Us[lr * 57 + x] = bf2f((unsigned short)pk[j]);
            }
        }
    }
    float w0 = w1c[c * 9 + 0], w1 = w1c[c * 9 + 1], w2 = w1c[c * 9 + 2];
    float w3 = w1c[c * 9 + 3], w4 = w1c[c * 9 + 4], w5 = w1c[c * 9 + 5];
    float w6 = w1c[c * 9 + 6], w7 = w1c[c * 9 + 7], w8 = w1c[c * 9 + 8];
    float s = g1[c] * rsqrtf(v1[c] + EPSF);
    float sh = b1[c] - m1[c] * s;
    __syncthreads();
    int c1lo = max(r0 - 1, 0), c1hi = min(r0 + 14, 55);
    int n1 = (c1hi - c1lo + 1) * 56;
    for (int i = tid; i < n1; i += 256) {
        int ry = i / 56, x = i - ry * 56;
        int gr = c1lo + ry;
        int liu = gr - (r0 - 2);
        float acc = dw3x3g(Us, liu, x, gr > 0, gr < 55,
                           w0, w1, w2, w3, w4, w5, w6, w7, w8);
        Cs[(gr - (r0 - 1)) * 57 + x] = acc * s + sh;
    }
    __syncthreads();
    if (tid < 16) {
        int qy = 2 * chunk + (tid >> 3), qx = tid & 7;
        const float* p0 = &Cs[(qy * 7 - (r0 - 1)) * 57 + qx * 7];
        float sm = 0.f, mx = -INFINITY;
#pragma unroll
        for (int py = 0; py < 7; py++)
#pragma unroll
            for (int px = 0; px < 7; px++) {
                float t = p0[py * 57 + px];
                sm += t;
                mx = fmaxf(mx, t);
            }
        oavg1[(size_t)bc * 64 + qy * 8 + qx] = sm * (1.f / 49.f);
        omax1[(size_t)bc * 64 + qy * 8 + qx] = mx;
    }
    for (int i = tid; i < n1; i += 256) {
        int ry = i / 56, x = i - ry * 56;
        int lr1 = (c1lo + ry) - (r0 - 1);
        Us[lr1 * 57 + x] = gelu_f(Cs[lr1 * 57 + x]);
    }
    w0 = w2c[c * 9 + 0]; w1 = w2c[c * 9 + 1]; w2 = w2c[c * 9 + 2];
    w3 = w2c[c * 9 + 3]; w4 = w2c[c * 9 + 4]; w5 = w2c[c * 9 + 5];
    w6 = w2c[c * 9 + 6]; w7 = w2c[c * 9 + 7]; w8 = w2c[c * 9 + 8];
    s = g2[c] * rsqrtf(v2[c] + EPSF);
    sh = b2[c] - m2[c] * s;
    __syncthreads();
    unsigned short* op = out + (size_t)bc * NN;
    for (int i = tid; i < 14 * 56; i += 256) {
        int ry = i / 56, x = i - ry * 56;
        int gr = r0 + ry;
        int lg = ry + 1;
        float val = dw3x3g(Us, lg, x, gr > 0, gr < 55,
                           w0, w1, w2, w3, w4, w5, w6, w7, w8) * s + sh;
        Cs[ry * 57 + x] = val;
        op[gr * 56 + x] = f2bf(val);
    }
    __syncthreads();
    if (tid < 16) {
        int qy = 2 * chunk + (tid >> 3), qx = tid & 7;
        const float* p0 = &Cs[((qy * 7) - r0) * 57 + qx * 7];
        float sm = 0.f, mx = -INFINITY;
#pragma unroll
        for (int py = 0; py < 7; py++)
#pragma unroll
            for (int px = 0; px < 7; px++) {
                float t = p0[py * 57 + px];
                sm += t;
                mx = fmaxf(mx, t);
            }
        oavg2[(size_t)bc * 64 + qy * 8 + qx] = sm * (1.f / 49.f);
        omax2[(size_t)bc * 64 + qy * 8 + qx] = mx;
    }
}

// ===========================================================================
// conv3 as MFMA GEMM (128x128 tile). Grid dim3(196, 2): x = m-tile.
// A-staging: full-line gather. lane -> (kk = lane>>2, no = lane&3):
// 4 lanes read the 4 x 16B chunks of one 64B line -> 16 distinct lines per
// instruction (was 64), every line fetched exactly once per block.
// ===========================================================================
__global__ __launch_bounds__(256) void conv3_mfma(
    const unsigned short* __restrict__ xin, const unsigned short* __restrict__ w16,
    const float* __restrict__ bias, const float* __restrict__ g,
    const float* __restrict__ bparm, const float* __restrict__ mm,
    const float* __restrict__ vvv, unsigned short* __restrict__ out16) {
    __shared__ short As[128 * 72];
    __shared__ short Bs[128 * 72];
    int m0 = blockIdx.x * 128, c0 = blockIdx.y * 128;
    int tid = threadIdx.x;
    int lane = tid & 63, wv = tid >> 6;
    int wm = wv >> 1, wc = wv & 1;
    int quad = lane >> 4, l16 = lane & 15;
    floatx4 zero = {0.f, 0.f, 0.f, 0.f};
    floatx4 acc[4][4];
#pragma unroll
    for (int mi = 0; mi < 4; mi++)
#pragma unroll
        for (int ci = 0; ci < 4; ci++) acc[mi][ci] = zero;

    for (int k0 = 0; k0 < 256; k0 += 64) {
        {
            int kk = lane >> 2, no = lane & 3;
            int rowb = wv * 32 + no * 8;      // local m base (wave strip of 32)
            int gn = m0 + rowb;
            int b8 = gn / NN, n8 = gn - b8 * NN;
#pragma unroll
            for (int ki = 0; ki < 4; ki++) {
                int c = k0 + ki * 16 + kk;
                short8 pk = *(const short8*)(const short*)(
                    xin + ((size_t)b8 * CC + c) * NN + n8);
                short* dst = &As[rowb * 72 + ki * 16 + kk];
#pragma unroll
                for (int j = 0; j < 8; j++) dst[j * 72] = pk[j];
            }
        }
#pragma unroll
        for (int i2 = 0; i2 < 4; i2++) {
            int idx = tid + 256 * i2;
            int c = idx >> 3, o = idx & 7;
            *(short8*)&Bs[c * 72 + o * 8] =
                *(const short8*)(const short*)(w16 + (size_t)(c0 + c) * CC + k0 + o * 8);
        }
        __syncthreads();
#pragma unroll
        for (int kc = 0; kc < 2; kc++) {
            short8 af[4], bf[4];
#pragma unroll
            for (int mi = 0; mi < 4; mi++)
                af[mi] = *(const short8*)&As[(wm * 64 + mi * 16 + l16) * 72 + (kc * 4 + quad) * 8];
#pragma unroll
            for (int ci = 0; ci < 4; ci++)
                bf[ci] = *(const short8*)&Bs[(wc * 64 + ci * 16 + l16) * 72 + (kc * 4 + quad) * 8];
#pragma unroll
            for (int mi = 0; mi < 4; mi++)
#pragma unroll
                for (int ci = 0; ci < 4; ci++)
                    acc[mi][ci] = __builtin_amdgcn_mfma_f32_16x16x32_bf16(
                        af[mi], bf[ci], acc[mi][ci], 0, 0, 0);
        }
        __syncthreads();
    }
#pragma unroll
    for (int ci = 0; ci < 4; ci++) {
        int co = c0 + wc * 64 + ci * 16 + l16;
        float s = g[co] * rsqrtf(vvv[co] + EPSF);
        float sh = bparm[co] - mm[co] * s;
        float bi = bias[co];
#pragma unroll
        for (int mi = 0; mi < 4; mi++) {
            int mbase = m0 + wm * 64 + mi * 16 + quad * 4;
#pragma unroll
            for (int r = 0; r < 4; r++) {
                float val = gelu_f((acc[mi][ci][r] + bi) * s + sh);
                out16[(size_t)(mbase + r) * CC + co] = f2bf(val);
            }
        }
    }
}

// ---------------------------------------------------------------------------
// attn_small[b,h,i,j] (fp32, 64x64 per (b,h)), pre-scaled by SCALEF,
// plus per-row max -> mq[bh*64 + i].
// ---------------------------------------------------------------------------
__global__ __launch_bounds__(256) void attn_qk_k(
    const float* __restrict__ q1, const float* __restrict__ q2,
    const float* __restrict__ k1, const float* __restrict__ k2,
    float* __restrict__ attn_s, float* __restrict__ mq) {
    int b = blockIdx.x >> 3, h = blockIdx.x & 7;
    __shared__ float Qs[64][64];
    __shared__ float Ks[64][64];
    __shared__ float pm[4][64];
    int tid = threadIdx.x;
#pragma unroll
    for (int l = 0; l < 16; l++) {
        int e = tid + 256 * l;
        int dt = e >> 6, i = e & 63;
        int d = dt & 31;
        const float* sq = (dt < 32) ? q1 : q2;
        const float* sk = (dt < 32) ? k1 : k2;
        Qs[dt][i] = sq[((size_t)b * CC + h * 32 + d) * NQ + i];
        Ks[dt][i] = sk[((size_t)b * CC + h * 32 + d) * NQ + i];
    }
    __syncthreads();
    int i = tid & 63, jg = tid >> 6;
    float acc[16] = {};
    for (int dt = 0; dt < 64; dt++) {
        float qv = Qs[dt][i];
#pragma unroll
        for (int t = 0; t < 16; t++) acc[t] += qv * Ks[dt][jg * 16 + t];
    }
    float mx = -INFINITY;
#pragma unroll
    for (int t = 0; t < 16; t++) {
        acc[t] *= SCALEF;
        mx = fmaxf(mx, acc[t]);
    }
    pm[jg][i] = mx;
    float* outp = attn_s + (((size_t)(b * 8 + h) * 64 + i) * 64) + jg * 16;
#pragma unroll
    for (int t = 0; t < 16; t++) outp[t] = acc[t];
    __syncthreads();
    if (tid < 64) {
        float m = fmaxf(fmaxf(pm[0][tid], pm[1][tid]),
                        fmaxf(pm[2][tid], pm[3][tid]));
        mq[(size_t)(b * 8 + h) * 64 + tid] = m;
    }
}

// ===========================================================================
// Split-K flash-style attention PV with MFMA. Scores pre-scaled, max
// precomputed; V tile + bilinear tables hoisted; one barrier total.
// ===========================================================================
__global__ __launch_bounds__(256) void attn_pv_k(
    const float* __restrict__ attn_s, const float* __restrict__ mq,
    const unsigned short* __restrict__ v16,
    float* __restrict__ part_O, float* __restrict__ part_rs) {
    __shared__ float asub[64][68];
    __shared__ unsigned short Vs[32][456];
    __shared__ short po4[448][4];
    __shared__ float pw4[448][4];
    int s = blockIdx.x, bh = blockIdx.y;
    int b = bh >> 3, h = bh & 7;
    int tid = threadIdx.x;
    int lane = tid & 63, wv = tid >> 6;
    int quad = lane >> 4, l16 = lane & 15;
    int q = wv * 16 + l16;
    float Mv = mq[(size_t)bh * 64 + q];
    {
        int qq = tid & 63, jg = tid >> 6;
        const float* src = attn_s + ((size_t)bh * 64 + qq) * 64 + jg * 16;
        float* dst = &asub[qq][jg * 16];
#pragma unroll
        for (int t = 0; t < 4; t++)
            *(floatx4*)(dst + t * 4) = *(const floatx4*)(src + t * 4);
    }
    {
        int d = tid >> 3, o0 = tid & 7;
        const unsigned short* vp =
            v16 + ((size_t)(b * CC + h * 32 + d)) * NN + s * 448;
#pragma unroll
        for (int t = 0; t < 7; t++) {
            int oc = o0 + t * 8;
            *(short8*)&Vs[d][oc * 8] = *(const short8*)(const short*)(vp + oc * 8);
        }
    }
    for (int idx = tid; idx < 448; idx += 256) {
        int n = s * 448 + idx;
        int oy = n / WWD, ox = n - oy * WWD;
        float sy = (oy + 0.5f) * 0.14285714285714285f - 0.5f;
        float sx = (ox + 0.5f) * 0.14285714285714285f - 0.5f;
        float fy0 = floorf(sy), fx0 = floorf(sx);
        int y0 = (int)fy0, x0 = (int)fx0;
        float fy = sy - fy0, fx = sx - fx0;
        int y0c = max(y0, 0), y1c = min(y0 + 1, 7);
        int x0c = max(x0, 0), x1c = min(x0 + 1, 7);
        po4[idx][0] = (short)(y0c * 8 + x0c);
        po4[idx][1] = (short)(y0c * 8 + x1c);
        po4[idx][2] = (short)(y1c * 8 + x0c);
        po4[idx][3] = (short)(y1c * 8 + x1c);
        pw4[idx][0] = (1.f - fy) * (1.f - fx);
        pw4[idx][1] = (1.f - fy) * fx;
        pw4[idx][2] = fy * (1.f - fx);
        pw4[idx][3] = fy * fx;
    }
    __syncthreads();
    floatx4 zero = {0.f, 0.f, 0.f, 0.f};
    floatx4 acc0 = zero, acc1 = zero;
    float rsum = 0.f;
    for (int cch = 0; cch < 7; cch++) {
#pragma unroll
        for (int kc = 0; kc < 2; kc++) {
            int col = cch * 64 + kc * 32 + quad * 8;
            short8 af;
#pragma unroll
            for (int j = 0; j < 8; j++) {
                int np = col + j;
                float val = pw4[np][0] * asub[q][po4[np][0]]
                          + pw4[np][1] * asub[q][po4[np][1]]
                          + pw4[np][2] * asub[q][po4[np][2]]
                          + pw4[np][3] * asub[q][po4[np][3]];
                float p = exp2f((val - Mv) * 1.44269504f);
                rsum += p;
                af[j] = (short)f2bf(p);
            }
            short8 bf0 = *(const short8*)&Vs[l16][col];
            short8 bf1 = *(const short8*)&Vs[16 + l16][col];
            acc0 = __builtin_amdgcn_mfma_f32_16x16x32_bf16(af, bf0, acc0, 0, 0, 0);
            acc1 = __builtin_amdgcn_mfma_f32_16x16x32_bf16(af, bf1, acc1, 0, 0, 0);
        }
    }
    rsum += __shfl_xor(rsum, 16, 64);
    rsum += __shfl_xor(rsum, 32, 64);
    size_t base = ((size_t)bh * 7 + s) * 64;
    if (lane < 16) part_rs[base + wv * 16 + lane] = rsum;
#pragma unroll
    for (int nt = 0; nt < 2; nt++) {
        floatx4 a = nt ? acc1 : acc0;
#pragma unroll
        for (int r = 0; r < 4; r++) {
            int qo = wv * 16 + quad * 4 + r;
            part_O[(base + qo) * 32 + nt * 16 + l16] = a[r];
        }
    }
}

// ===========================================================================
// Fused split-K reduction + bilinear upsample + dw 3x3 + vbn -> x_low.
// ===========================================================================
__global__ __launch_bounds__(256) void upconv_k(
    const float* __restrict__ part_O, const float* __restrict__ part_rs,
    const float* __restrict__ w,
    const float* __restrict__ g, const float* __restrict__ bparm,
    const float* __restrict__ m, const float* __restrict__ v,
    unsigned short* __restrict__ xlow16) {
    __shared__ float ts[64];
    __shared__ float Us[16 * 57];
    int bid = blockIdx.x;
    int bc = bid >> 2, chunk = bid & 3;
    int c = bc & 255;
    int r0 = chunk * 14;
    int tid = threadIdx.x;
    if (tid < 64) {
        int h = c >> 5, d = c & 31;
        int bh = (bc >> 8) * 8 + h;
        float o = 0.f, rs = 0.f;
        for (int s7 = 0; s7 < 7; s7++) {
            size_t base = ((size_t)bh * 7 + s7) * 64 + tid;
            o += part_O[base * 32 + d];
            rs += part_rs[base];
        }
        ts[tid] = o / rs;
    }
    __syncthreads();
    int blo = max(r0 - 1, 0), bhi = min(r0 + 14, 55);
    int nb = (bhi - blo + 1) * 56;
    for (int i = tid; i < nb; i += 256) {
        int ry = i / 56, x = i - ry * 56;
        int gr = blo + ry;
        float sy = (gr + 0.5f) * 0.14285714285714285f - 0.5f;
        float sx = (x + 0.5f) * 0.14285714285714285f - 0.5f;
        float fy0 = floorf(sy), fx0 = floorf(sx);
        int y0 = (int)fy0, x0 = (int)fx0;
        float fy = sy - fy0, fx = sx - fx0;
        int y0c = max(y0, 0), y1c = min(y0 + 1, 7);
        int x0c = max(x0, 0), x1c = min(x0 + 1, 7);
        float v00 = ts[y0c * 8 + x0c], v01 = ts[y0c * 8 + x1c];
        float v10 = ts[y1c * 8 + x0c], v11 = ts[y1c * 8 + x1c];
        Us[(gr - (r0 - 1)) * 57 + x] =
            (1.f - fy) * ((1.f - fx) * v00 + fx * v01) +
            fy * ((1.f - fx) * v10 + fx * v11);
    }
    float w0 = w[c * 9 + 0], w1 = w[c * 9 + 1], w2 = w[c * 9 + 2];
    float w3 = w[c * 9 + 3], w4 = w[c * 9 + 4], w5 = w[c * 9 + 5];
    float w6 = w[c * 9 + 6], w7 = w[c * 9 + 7], w8 = w[c * 9 + 8];
    float s = g[c] * rsqrtf(v[c] + EPSF);
    float sh = bparm[c] - m[c] * s;
    __syncthreads();
    unsigned short* op = xlow16 + (size_t)bc * NN;
    for (int i = tid; i < 14 * 56; i += 256) {
        int ry = i / 56, x = i - ry * 56;
        int gr = r0 + ry;
        float val = dw3x3g(Us, ry + 1, x, gr > 0, gr < 55,
                           w0, w1, w2, w3, w4, w5, w6, w7, w8);
        op[gr * 56 + x] = f2bf(val * s + sh);
    }
}

// ===========================================================================
// Final projection MFMA (128x128 tile). Grid dim3(196, 4): x = m-tile.
// xl half uses the full-line gather (16 lines/instruction).
// ===========================================================================
__global__ __launch_bounds__(256) void proj_mfma(
    const unsigned short* __restrict__ xh16, const unsigned short* __restrict__ xl16,
    const unsigned short* __restrict__ w16, const float* __restrict__ bias,
    float* __restrict__ y) {
    __shared__ short As[128 * 72];
    __shared__ short Bs[128 * 72];
    int m0 = blockIdx.x * 128, c0 = blockIdx.y * 128;
    int tid = threadIdx.x;
    int lane = tid & 63, wv = tid >> 6;
    int wm = wv >> 1, wc = wv & 1;
    int quad = lane >> 4, l16 = lane & 15;
    floatx4 zero = {0.f, 0.f, 0.f, 0.f};
    floatx4 acc[4][4];
#pragma unroll
    for (int mi = 0; mi < 4; mi++)
#pragma unroll
        for (int ci = 0; ci < 4; ci++) acc[mi][ci] = zero;

    for (int k0 = 0; k0 < 512; k0 += 64) {
        if (k0 < 256) {
#pragma unroll
            for (int i2 = 0; i2 < 4; i2++) {
                int idx = tid + 256 * i2;
                int m = idx >> 3, o = idx & 7;
                *(short8*)&As[m * 72 + o * 8] =
                    *(const short8*)(const short*)(xh16 + (size_t)(m0 + m) * CC + k0 + o * 8);
            }
        } else {
            int kk = lane >> 2, no = lane & 3;
            int rowb = wv * 32 + no * 8;
            int gn = m0 + rowb;
            int b8 = gn / NN, n8 = gn - b8 * NN;
#pragma unroll
            for (int ki = 0; ki < 4; ki++) {
                int c = (k0 - 256) + ki * 16 + kk;
                short8 pk = *(const short8*)(const short*)(
                    xl16 + ((size_t)b8 * CC + c) * NN + n8);
                short* dst = &As[rowb * 72 + ki * 16 + kk];
#pragma unroll
                for (int j = 0; j < 8; j++) dst[j * 72] = pk[j];
            }
        }
#pragma unroll
        for (int i2 = 0; i2 < 4; i2++) {
            int idx = tid + 256 * i2;
            int c = idx >> 3, o = idx & 7;
            *(short8*)&Bs[c * 72 + o * 8] =
                *(const short8*)(const short*)(w16 + (size_t)(c0 + c) * DIMM + k0 + o * 8);
        }
        __syncthreads();
#pragma unroll
        for (int kc = 0; kc < 2; kc++) {
            short8 af[4], bf[4];
#pragma unroll
            for (int mi = 0; mi < 4; mi++)
                af[mi] = *(const short8*)&As[(wm * 64 + mi * 16 + l16) * 72 + (kc * 4 + quad) * 8];
#pragma unroll
            for (int ci = 0; ci < 4; ci++)
                bf[ci] = *(const short8*)&Bs[(wc * 64 + ci * 16 + l16) * 72 + (kc * 4 + quad) * 8];
#pragma unroll
            for (int mi = 0; mi < 4; mi++)
#pragma unroll
                for (int ci = 0; ci < 4; ci++)
                    acc[mi][ci] = __builtin_amdgcn_mfma_f32_16x16x32_bf16(
                        af[mi], bf[ci], acc[mi][ci], 0, 0, 0);
        }
        __syncthreads();
    }
#pragma unroll
    for (int mi = 0; mi < 4; mi++) {
        int mbase = m0 + wm * 64 + mi * 16 + quad * 4;
#pragma unroll
        for (int ci = 0; ci < 4; ci++) {
            int co = c0 + wc * 64 + ci * 16 + l16;
            float bi = bias[co];
#pragma unroll
            for (int r = 0; r < 4; r++)
                y[(size_t)(mbase + r) * DIMM + co] = acc[mi][ci][r] + bi;
        }
    }
}

extern "C" void kernel_launch(void* const* d_in, const int* in_sizes, int n_in,
                              void* d_out, int out_size, void* d_ws, size_t ws_size,
                              hipStream_t stream) {
    const float* x        = (const float*)d_in[0];
    const float* proj_v_w = (const float*)d_in[1];
    const float* conv1_w  = (const float*)d_in[2];
    const float* conv2_w  = (const float*)d_in[3];
    const float* conv3_w  = (const float*)d_in[4];
    const float* conv3_b  = (const float*)d_in[5];
    const float* v_conv_w = (const float*)d_in[6];
    const float* proj_w   = (const float*)d_in[7];
    const float* proj_b   = (const float*)d_in[8];
    const float* bn1_g = (const float*)d_in[9],  *bn1_b = (const float*)d_in[10];
    const float* bn1_m = (const float*)d_in[11], *bn1_v = (const float*)d_in[12];
    const float* bn2_g = (const float*)d_in[13], *bn2_b = (const float*)d_in[14];
    const float* bn2_m = (const float*)d_in[15], *bn2_v = (const float*)d_in[16];
    const float* bn3_g = (const float*)d_in[17], *bn3_b = (const float*)d_in[18];
    const float* bn3_m = (const float*)d_in[19], *bn3_v = (const float*)d_in[20];
    const float* vbn_g = (const float*)d_in[21], *vbn_b = (const float*)d_in[22];
    const float* vbn_m = (const float*)d_in[23], *vbn_v = (const float*)d_in[24];

    const size_t big = (size_t)BB * CC * NN;  // 6,422,528 elements
    unsigned short* v16    = (unsigned short*)d_ws;       // v bf16 NCHW
    unsigned short* bufA16 = v16 + big;                   // (unused, layout kept)
    unsigned short* bufB16 = bufA16 + big;                // bn2 bf16 NCHW
    unsigned short* xh16   = bufB16 + big;                // x_high bf16 (B,N,C)
    unsigned short* xlow16 = xh16 + big;                  // x_low bf16 NCHW
    float* small = (float*)(xlow16 + big);
    float* q1 = small;
    float* q2 = q1 + (size_t)BB * CC * NQ;
    float* k1 = q2 + (size_t)BB * CC * NQ;
    float* k2 = k1 + (size_t)BB * CC * NQ;
    float* attn_s = k2 + (size_t)BB * CC * NQ;               // (B,NH,64,64)
    float* out_s  = attn_s + (size_t)BB * NHEAD * NQ * NQ;   // (unused)
    float* part_O = out_s + (size_t)BB * CC * NQ;            // 64*7*64*32
    float* part_rs = part_O + (size_t)64 * 7 * 64 * 32;      // 64*7*64
    float* mq = part_rs + (size_t)64 * 7 * 64;               // 64*64
    unsigned short* w16v  = (unsigned short*)(mq + 64 * 64);
    unsigned short* w16c3 = w16v + 65536;
    unsigned short* w16p  = w16c3 + 65536;  // 262144 shorts

    cast3_k<<<1024, 256, 0, stream>>>(proj_v_w, conv3_w, proj_w, w16v, w16c3, w16p);

    gemm_v_mfma<<<dim3(196, 2), 256, 0, stream>>>(x, w16v, v16);
    dwconv2x_k<<<BB * CC * 4, 256, 0, stream>>>(
        v16, conv1_w, bn1_g, bn1_b, bn1_m, bn1_v,
        conv2_w, bn2_g, bn2_b, bn2_m, bn2_v, bufB16, q1, q2, k1, k2);
    conv3_mfma<<<dim3(196, 2), 256, 0, stream>>>(bufB16, w16c3, conv3_b,
                                                 bn3_g, bn3_b, bn3_m, bn3_v, xh16);
    attn_qk_k<<<64, 256, 0, stream>>>(q1, q2, k1, k2, attn_s, mq);
    attn_pv_k<<<dim3(7, 64), 256, 0, stream>>>(attn_s, mq, v16, part_O, part_rs);
    upconv_k<<<BB * CC * 4, 256, 0, stream>>>(part_O, part_rs, v_conv_w,
                                              vbn_g, vbn_b, vbn_m, vbn_v, xlow16);
    proj_mfma<<<dim3(196, 4), 256, 0, stream>>>(xh16, xlow16, w16p, proj_b,
                                                (float*)d_out);
}